// Round 12
// baseline (152.826 us; speedup 1.0000x reference)
//
#include <hip/hip_runtime.h>
#include <math.h>

// TripletHard B=8192 D=128 NC=256. Round-12: r10's proven hot-loop config
// (lb(256,3), 768 blocks, 32x64 wave tile, 16 j-tiles) + r11's lsq packing
// + merge FUSED into work as a last-block epilogue (threadfence release/
// acquire + device-scope counter) -> 2 launches total.
//   prep : fp32->bf16 (RNE), K-major fbT, lsq=(sq,lblbits) of rounded values.
//   work : 768 blocks = 256 CU x 3. [0,512): neg-only diff-class min.
//          [512,768): per-class Gram -> 2nd-smallest same-class d2.
//          Last block to finish computes the mean hinge.
// fbT8[kc*8192 + row] = features[row][kc*8..kc*8+7], kc=0..15.

#define BN 8192
#define MARGIN_F 1.0f
#define EPS_F 1e-5f

typedef __attribute__((ext_vector_type(8))) short short8;
typedef __attribute__((ext_vector_type(4))) float floatx4;

__device__ __forceinline__ unsigned short bf16_rne(float x, float& r) {
    unsigned u = __float_as_uint(x);
    u += 0x7FFF + ((u >> 16) & 1);
    unsigned short h = (unsigned short)(u >> 16);
    r = __uint_as_float(((unsigned)h) << 16);
    return h;
}

// 8 threads/row (256 blocks): bf16 convert, K-major write, lsq=(sq, lblbits)
// from ROUNDED values. Also zero-inits counter.
__global__ __launch_bounds__(256) void prep_kernel(const float* __restrict__ f,
                                                   const int* __restrict__ lbl,
                                                   short8* __restrict__ fbT,
                                                   float2* __restrict__ lsq,
                                                   unsigned* __restrict__ counter) {
    int gid = blockIdx.x * 256 + threadIdx.x;  // 0..65535
    if (gid == 0) { *counter = 0u; }
    int row = gid >> 3, part = gid & 7;
    const float4* f4 = (const float4*)f + (size_t)row * 32 + part * 4;
    float s = 0.f;
#pragma unroll
    for (int cc = 0; cc < 2; ++cc) {  // chunk kc = part*2 + cc
        float4 v0 = f4[cc * 2], v1 = f4[cc * 2 + 1];
        float r0, r1, r2, r3, r4, r5, r6, r7;
        short8 o;
        o[0] = (short)bf16_rne(v0.x, r0);
        o[1] = (short)bf16_rne(v0.y, r1);
        o[2] = (short)bf16_rne(v0.z, r2);
        o[3] = (short)bf16_rne(v0.w, r3);
        o[4] = (short)bf16_rne(v1.x, r4);
        o[5] = (short)bf16_rne(v1.y, r5);
        o[6] = (short)bf16_rne(v1.z, r6);
        o[7] = (short)bf16_rne(v1.w, r7);
        fbT[(size_t)(part * 2 + cc) * BN + row] = o;
        s += r0 * r0 + r1 * r1 + r2 * r2 + r3 * r3 +
             r4 * r4 + r5 * r5 + r6 * r6 + r7 * r7;
    }
    s += __shfl_xor(s, 1, 8);
    s += __shfl_xor(s, 2, 8);
    s += __shfl_xor(s, 4, 8);
    if (part == 0) {
        float2 p;
        p.x = s;
        p.y = __int_as_float(lbl[row]);
        lsq[row] = p;
    }
}

// Fused work kernel. Blocks [0,512): main (gen-1 resident). [512,768): pos.
// Last finisher computes the mean hinge (release/acquire via threadfence).
__global__ __launch_bounds__(256, 3) void work_kernel(const short8* __restrict__ fbT,
                                                      const int* __restrict__ lbl,
                                                      const float2* __restrict__ lsq,
                                                      float* __restrict__ part,
                                                      float* __restrict__ pos_d2,
                                                      unsigned* __restrict__ counter,
                                                      float* __restrict__ out) {
    const int t = threadIdx.x;
    const int lane = t & 63;
    const int wv = t >> 6;
    const int q = lane >> 4, c = lane & 15;
    const int bid = blockIdx.x;
    __shared__ unsigned s_rank;
    __shared__ float red[4];

    if (bid >= 512) {
        // ---------------- pos path: per-class 2nd-smallest same-class d2 ---
        __shared__ int midx[256];
        __shared__ int cnt;
        const int cls = bid - 512;
        if (t == 0) cnt = 0;
        __syncthreads();
        for (int r = t; r < BN; r += 256) {
            if (lbl[r] == cls) {
                int p = atomicAdd(&cnt, 1);
                if (p < 256) midx[p] = r;
            }
        }
        __syncthreads();
        int n = cnt < 256 ? cnt : 256;
        if (n > 0) {
            if (t < 256 && t >= n) midx[t] = midx[0];  // pad
            __syncthreads();

            const int ng = (n + 15) >> 4;  // 16-row groups per wave
            for (int ig = wv; ig < ng; ig += 4) {
                short8 a[4];
                int arow = midx[ig * 16 + c];
#pragma unroll
                for (int ks = 0; ks < 4; ++ks)
                    a[ks] = fbT[(size_t)(ks * 4 + q) * BN + arow];
                float s1[4], s2[4];
#pragma unroll
                for (int rg = 0; rg < 4; ++rg) { s1[rg] = INFINITY; s2[rg] = INFINITY; }

                for (int s = 0; s < ng; ++s) {  // 16 j-slots per step
                    int jslot = s * 16 + c;
                    int jrow = midx[jslot];
                    short8 b[4];
#pragma unroll
                    for (int ks = 0; ks < 4; ++ks)
                        b[ks] = fbT[(size_t)(ks * 4 + q) * BN + jrow];
                    float sj = lsq[jrow].x;
                    bool valid = (jslot < n);

                    floatx4 acc = (floatx4)0.f;
#pragma unroll
                    for (int ks = 0; ks < 4; ++ks)
                        acc = __builtin_amdgcn_mfma_f32_16x16x32_bf16(a[ks], b[ks], acc, 0, 0, 0);
#pragma unroll
                    for (int rg = 0; rg < 4; ++rg) {
                        float v = fmaf(-2.0f, acc[rg], sj);
                        float vs = valid ? v : INFINITY;
                        s2[rg] = fminf(s2[rg], fmaxf(s1[rg], vs));
                        s1[rg] = fminf(s1[rg], vs);
                    }
                }
#pragma unroll
                for (int m = 1; m < 16; m <<= 1) {
#pragma unroll
                    for (int rg = 0; rg < 4; ++rg) {
                        float o1 = __shfl_xor(s1[rg], m, 16);
                        float o2 = __shfl_xor(s2[rg], m, 16);
                        float lo = fminf(s1[rg], o1);
                        float hi = fminf(fmaxf(s1[rg], o1), fminf(s2[rg], o2));
                        s1[rg] = lo; s2[rg] = hi;
                    }
                }
                if (c == 0) {
#pragma unroll
                    for (int rg = 0; rg < 4; ++rg) {
                        int islot = ig * 16 + q * 4 + rg;
                        if (islot < n) {
                            int row = midx[islot];
                            pos_d2[row] = lsq[row].x + s2[rg];
                        }
                    }
                }
            }
        }
    } else {
        // ------- main path: diff-class min, wave tile 32x64, 16 j-tiles ---
        const int i0 = (bid & 63) * 128 + wv * 32;
        const int g = bid >> 6;  // 0..7
        const int jb = g * 1024;

        short8 a[2][4];
#pragma unroll
        for (int mf = 0; mf < 2; ++mf) {
            int row = i0 + mf * 16 + c;
#pragma unroll
            for (int ks = 0; ks < 4; ++ks)
                a[mf][ks] = fbT[(size_t)(ks * 4 + q) * BN + row];
        }
        int li[2][4];
#pragma unroll
        for (int mf = 0; mf < 2; ++mf)
#pragma unroll
            for (int rg = 0; rg < 4; ++rg)
                li[mf][rg] = __float_as_int(lsq[i0 + mf * 16 + q * 4 + rg].y);

        float n1[2][4];
#pragma unroll
        for (int mf = 0; mf < 2; ++mf)
#pragma unroll
            for (int rg = 0; rg < 4; ++rg) n1[mf][rg] = INFINITY;

#pragma unroll 2
        for (int jt = 0; jt < 16; ++jt) {
            const int j0 = jb + jt * 64;

            int ljv[4]; float sjv[4];
#pragma unroll
            for (int nf = 0; nf < 4; ++nf) {
                float2 p = lsq[j0 + nf * 16 + c];
                sjv[nf] = p.x;
                ljv[nf] = __float_as_int(p.y);
            }

            floatx4 acc[2][4];
#pragma unroll
            for (int mf = 0; mf < 2; ++mf)
#pragma unroll
                for (int nf = 0; nf < 4; ++nf) acc[mf][nf] = (floatx4)0.f;

#pragma unroll
            for (int ks = 0; ks < 4; ++ks) {
                short8 b[4];
#pragma unroll
                for (int nf = 0; nf < 4; ++nf)
                    b[nf] = fbT[(size_t)(ks * 4 + q) * BN + j0 + nf * 16 + c];
#pragma unroll
                for (int mf = 0; mf < 2; ++mf)
#pragma unroll
                    for (int nf = 0; nf < 4; ++nf)
                        acc[mf][nf] = __builtin_amdgcn_mfma_f32_16x16x32_bf16(
                            a[mf][ks], b[nf], acc[mf][nf], 0, 0, 0);
            }

            // neg-only epilogue: 4 ops/element
#pragma unroll
            for (int nf = 0; nf < 4; ++nf) {
#pragma unroll
                for (int mf = 0; mf < 2; ++mf)
#pragma unroll
                    for (int rg = 0; rg < 4; ++rg) {
                        float v = fmaf(-2.0f, acc[mf][nf][rg], sjv[nf]);
                        float vd = (li[mf][rg] == ljv[nf]) ? INFINITY : v;
                        n1[mf][rg] = fminf(n1[mf][rg], vd);
                    }
            }
        }

        // min across the 16 c-lanes sharing each accumulator row
#pragma unroll
        for (int m = 1; m < 16; m <<= 1) {
#pragma unroll
            for (int mf = 0; mf < 2; ++mf)
#pragma unroll
                for (int rg = 0; rg < 4; ++rg)
                    n1[mf][rg] = fminf(n1[mf][rg], __shfl_xor(n1[mf][rg], m, 16));
        }
        if (c == 0) {
#pragma unroll
            for (int mf = 0; mf < 2; ++mf)
#pragma unroll
                for (int rg = 0; rg < 4; ++rg)
                    part[g * BN + i0 + mf * 16 + q * 4 + rg] = n1[mf][rg];
        }
    }

    // ---- fused finalize: last block computes the mean hinge -------------
    __threadfence();  // release: part/pos_d2 visible device-wide
    if (t == 0) s_rank = atomicAdd(counter, 1u);
    __syncthreads();
    if (s_rank == 767u) {
        __threadfence();  // acquire
        float sum = 0.f;
        for (int it = 0; it < 32; ++it) {
            int r = it * 256 + t;
            float n = INFINITY;
#pragma unroll
            for (int k = 0; k < 8; ++k) n = fminf(n, part[k * BN + r]);
            float pos = sqrtf(fmaxf(pos_d2[r] + EPS_F, 0.f));
            float neg = sqrtf(fmaxf(lsq[r].x + n + EPS_F, 0.f));
            sum += fmaxf(MARGIN_F + pos - neg, 0.f);
        }
#pragma unroll
        for (int m = 32; m >= 1; m >>= 1) sum += __shfl_down(sum, m, 64);
        if (lane == 0) red[wv] = sum;
        __syncthreads();
        if (t == 0) out[0] = (red[0] + red[1] + red[2] + red[3]) / (float)BN;
    }
}

extern "C" void kernel_launch(void* const* d_in, const int* in_sizes, int n_in,
                              void* d_out, int out_size, void* d_ws, size_t ws_size,
                              hipStream_t stream) {
    const float* f = (const float*)d_in[0];
    const int* lbl = (const int*)d_in[1];
    char* ws = (char*)d_ws;
    float2* lsq = (float2*)ws;                                 // 64 KB
    short8* fbT = (short8*)(ws + 65536);                       // 2 MB
    float* part = (float*)(ws + 65536 + 2097152);              // 256 KB (8 slices)
    float* pos_d2 = (float*)(ws + 65536 + 2097152 + 262144);   // 32 KB
    unsigned* counter = (unsigned*)(ws + 65536 + 2097152 + 262144 + 32768);
    float* out = (float*)d_out;

    prep_kernel<<<256, 256, 0, stream>>>(f, lbl, fbT, lsq, counter);
    work_kernel<<<768, 256, 0, stream>>>(fbT, lbl, lsq, part, pos_d2, counter, out);
}

// Round 13
// 89.214 us; speedup vs baseline: 1.7130x; 1.7130x over previous
//
#include <hip/hip_runtime.h>
#include <math.h>

// TripletHard B=8192 D=128 NC=256. Round-13 = r10 (proven 88 us) +
// raw s_barrier wave-lockstep in the main jt loop (L1/MSHR reuse of the
// shared B-tile across the block's 4 waves) + 8-thread/row prep.
// r12 lesson: do NOT fuse the finalize into work (register-budget poisoning:
// VGPR 150->68, 3x regression). 3 launches.
//   prep : fp32->bf16 (RNE), K-major fbT, sq of rounded values.
//   work : 768 blocks = 256 CU x 3. [0,512): neg-only diff-class min, wave
//          tile 32x64 (mf=2), A-frags resident, 16 j-tiles, lockstep waves.
//          [512,768): per-class Gram -> 2nd-smallest same-class d2 (pos_d2).
//   merge: combine 8 n1 slices + pos_d2 -> mean hinge (device atomics).
// fbT8[kc*8192 + row] = features[row][kc*8..kc*8+7], kc=0..15.

#define BN 8192
#define MARGIN_F 1.0f
#define EPS_F 1e-5f

typedef __attribute__((ext_vector_type(8))) short short8;
typedef __attribute__((ext_vector_type(4))) float floatx4;

__device__ __forceinline__ unsigned short bf16_rne(float x, float& r) {
    unsigned u = __float_as_uint(x);
    u += 0x7FFF + ((u >> 16) & 1);
    unsigned short h = (unsigned short)(u >> 16);
    r = __uint_as_float(((unsigned)h) << 16);
    return h;
}

// 8 threads/row (256 blocks): bf16 convert, K-major write, sq from ROUNDED
// values. Also zero-inits g_acc/counter.
__global__ __launch_bounds__(256) void prep_kernel(const float* __restrict__ f,
                                                   short8* __restrict__ fbT,
                                                   float* __restrict__ sq,
                                                   float* __restrict__ g_acc,
                                                   unsigned* __restrict__ counter) {
    int gid = blockIdx.x * 256 + threadIdx.x;  // 0..65535
    if (gid == 0) { *g_acc = 0.f; *counter = 0u; }
    int row = gid >> 3, part = gid & 7;
    const float4* f4 = (const float4*)f + (size_t)row * 32 + part * 4;
    float s = 0.f;
#pragma unroll
    for (int cc = 0; cc < 2; ++cc) {  // chunk kc = part*2 + cc
        float4 v0 = f4[cc * 2], v1 = f4[cc * 2 + 1];
        float r0, r1, r2, r3, r4, r5, r6, r7;
        short8 o;
        o[0] = (short)bf16_rne(v0.x, r0);
        o[1] = (short)bf16_rne(v0.y, r1);
        o[2] = (short)bf16_rne(v0.z, r2);
        o[3] = (short)bf16_rne(v0.w, r3);
        o[4] = (short)bf16_rne(v1.x, r4);
        o[5] = (short)bf16_rne(v1.y, r5);
        o[6] = (short)bf16_rne(v1.z, r6);
        o[7] = (short)bf16_rne(v1.w, r7);
        fbT[(size_t)(part * 2 + cc) * BN + row] = o;
        s += r0 * r0 + r1 * r1 + r2 * r2 + r3 * r3 +
             r4 * r4 + r5 * r5 + r6 * r6 + r7 * r7;
    }
    s += __shfl_xor(s, 1, 8);
    s += __shfl_xor(s, 2, 8);
    s += __shfl_xor(s, 4, 8);
    if (part == 0) sq[row] = s;
}

// Fused work kernel. Blocks [0,512): main (gen-1 resident). [512,768): pos.
__global__ __launch_bounds__(256, 3) void work_kernel(const short8* __restrict__ fbT,
                                                      const int* __restrict__ lbl,
                                                      const float* __restrict__ sq,
                                                      float* __restrict__ part,
                                                      float* __restrict__ pos_d2) {
    const int t = threadIdx.x;
    const int lane = t & 63;
    const int wv = t >> 6;
    const int q = lane >> 4, c = lane & 15;
    const int bid = blockIdx.x;

    if (bid >= 512) {
        // ---------------- pos path: per-class 2nd-smallest same-class d2 ---
        __shared__ int midx[256];
        __shared__ int cnt;
        const int cls = bid - 512;
        if (t == 0) cnt = 0;
        __syncthreads();
        for (int r = t; r < BN; r += 256) {
            if (lbl[r] == cls) {
                int p = atomicAdd(&cnt, 1);
                if (p < 256) midx[p] = r;
            }
        }
        __syncthreads();
        int n = cnt < 256 ? cnt : 256;
        if (n == 0) return;
        if (t < 256 && t >= n) midx[t] = midx[0];  // pad
        __syncthreads();

        const int ng = (n + 15) >> 4;  // 16-row groups; wave wv takes ig = wv, wv+4, ...
        for (int ig = wv; ig < ng; ig += 4) {
            short8 a[4];
            int arow = midx[ig * 16 + c];
#pragma unroll
            for (int ks = 0; ks < 4; ++ks)
                a[ks] = fbT[(size_t)(ks * 4 + q) * BN + arow];
            float s1[4], s2[4];
#pragma unroll
            for (int rg = 0; rg < 4; ++rg) { s1[rg] = INFINITY; s2[rg] = INFINITY; }

            for (int s = 0; s < ng; ++s) {  // 16 j-slots per step
                int jslot = s * 16 + c;
                int jrow = midx[jslot];
                short8 b[4];
#pragma unroll
                for (int ks = 0; ks < 4; ++ks)
                    b[ks] = fbT[(size_t)(ks * 4 + q) * BN + jrow];
                float sj = sq[jrow];
                bool valid = (jslot < n);

                floatx4 acc = (floatx4)0.f;
#pragma unroll
                for (int ks = 0; ks < 4; ++ks)
                    acc = __builtin_amdgcn_mfma_f32_16x16x32_bf16(a[ks], b[ks], acc, 0, 0, 0);
#pragma unroll
                for (int rg = 0; rg < 4; ++rg) {
                    float v = fmaf(-2.0f, acc[rg], sj);
                    float vs = valid ? v : INFINITY;
                    s2[rg] = fminf(s2[rg], fmaxf(s1[rg], vs));
                    s1[rg] = fminf(s1[rg], vs);
                }
            }
#pragma unroll
            for (int m = 1; m < 16; m <<= 1) {
#pragma unroll
                for (int rg = 0; rg < 4; ++rg) {
                    float o1 = __shfl_xor(s1[rg], m, 16);
                    float o2 = __shfl_xor(s2[rg], m, 16);
                    float lo = fminf(s1[rg], o1);
                    float hi = fminf(fmaxf(s1[rg], o1), fminf(s2[rg], o2));
                    s1[rg] = lo; s2[rg] = hi;
                }
            }
            if (c == 0) {
#pragma unroll
                for (int rg = 0; rg < 4; ++rg) {
                    int islot = ig * 16 + q * 4 + rg;
                    if (islot < n) {
                        int row = midx[islot];
                        pos_d2[row] = sq[row] + s2[rg];
                    }
                }
            }
        }
        return;
    }

    // ------- main path: diff-class min, wave tile 32x64, 16 j-tiles -------
    const int i0 = (bid & 63) * 128 + wv * 32;  // 64 i-blocks x 4 waves x 32 rows
    const int g = bid >> 6;  // 0..7
    const int jb = g * 1024;

    short8 a[2][4];
#pragma unroll
    for (int mf = 0; mf < 2; ++mf) {
        int row = i0 + mf * 16 + c;
#pragma unroll
        for (int ks = 0; ks < 4; ++ks)
            a[mf][ks] = fbT[(size_t)(ks * 4 + q) * BN + row];
    }
    int li[2][4];
#pragma unroll
    for (int mf = 0; mf < 2; ++mf)
#pragma unroll
        for (int rg = 0; rg < 4; ++rg)
            li[mf][rg] = lbl[i0 + mf * 16 + q * 4 + rg];

    float n1[2][4];
#pragma unroll
    for (int mf = 0; mf < 2; ++mf)
#pragma unroll
        for (int rg = 0; rg < 4; ++rg) n1[mf][rg] = INFINITY;

#pragma unroll 2
    for (int jt = 0; jt < 16; ++jt) {
        // raw barrier (NO waitcnt drain): keeps the block's 4 waves in
        // lockstep so their identical b-addresses hit L1/MSHR-coalesce.
        __builtin_amdgcn_s_barrier();
        const int j0 = jb + jt * 64;

        int ljv[4]; float sjv[4];
#pragma unroll
        for (int nf = 0; nf < 4; ++nf) {
            int jc = j0 + nf * 16 + c;
            ljv[nf] = lbl[jc];
            sjv[nf] = sq[jc];
        }

        floatx4 acc[2][4];
#pragma unroll
        for (int mf = 0; mf < 2; ++mf)
#pragma unroll
            for (int nf = 0; nf < 4; ++nf) acc[mf][nf] = (floatx4)0.f;

#pragma unroll
        for (int ks = 0; ks < 4; ++ks) {
            short8 b[4];
#pragma unroll
            for (int nf = 0; nf < 4; ++nf)
                b[nf] = fbT[(size_t)(ks * 4 + q) * BN + j0 + nf * 16 + c];
#pragma unroll
            for (int mf = 0; mf < 2; ++mf)
#pragma unroll
                for (int nf = 0; nf < 4; ++nf)
                    acc[mf][nf] = __builtin_amdgcn_mfma_f32_16x16x32_bf16(
                        a[mf][ks], b[nf], acc[mf][nf], 0, 0, 0);
        }

        // neg-only epilogue: 4 ops/element
#pragma unroll
        for (int nf = 0; nf < 4; ++nf) {
#pragma unroll
            for (int mf = 0; mf < 2; ++mf)
#pragma unroll
                for (int rg = 0; rg < 4; ++rg) {
                    float v = fmaf(-2.0f, acc[mf][nf][rg], sjv[nf]);
                    float vd = (li[mf][rg] == ljv[nf]) ? INFINITY : v;
                    n1[mf][rg] = fminf(n1[mf][rg], vd);
                }
        }
    }

    // min across the 16 c-lanes sharing each accumulator row
#pragma unroll
    for (int m = 1; m < 16; m <<= 1) {
#pragma unroll
        for (int mf = 0; mf < 2; ++mf)
#pragma unroll
            for (int rg = 0; rg < 4; ++rg)
                n1[mf][rg] = fminf(n1[mf][rg], __shfl_xor(n1[mf][rg], m, 16));
    }
    if (c == 0) {
#pragma unroll
        for (int mf = 0; mf < 2; ++mf)
#pragma unroll
            for (int rg = 0; rg < 4; ++rg)
                part[g * BN + i0 + mf * 16 + q * 4 + rg] = n1[mf][rg];
    }
}

// combine 8 n1 slices + pos_d2 -> hinge; atomic sum; last block writes mean
__global__ __launch_bounds__(128) void merge_kernel(const float* __restrict__ part,
                                                    const float* __restrict__ sq,
                                                    const float* __restrict__ pos_d2,
                                                    float* __restrict__ g_acc,
                                                    unsigned* __restrict__ counter,
                                                    float* __restrict__ out) {
    int r = blockIdx.x * 128 + threadIdx.x;
    float n = INFINITY;
#pragma unroll
    for (int k = 0; k < 8; ++k) n = fminf(n, part[k * BN + r]);
    float si = sq[r];
    float pos = sqrtf(fmaxf(pos_d2[r] + EPS_F, 0.f));
    float neg = sqrtf(fmaxf(si + n + EPS_F, 0.f));
    float h = fmaxf(MARGIN_F + pos - neg, 0.f);
    __shared__ float red[2];
#pragma unroll
    for (int m = 32; m >= 1; m >>= 1) h += __shfl_down(h, m, 64);
    if ((threadIdx.x & 63) == 0) red[threadIdx.x >> 6] = h;
    __syncthreads();
    if (threadIdx.x == 0) {
        atomicAdd(g_acc, red[0] + red[1]);
        __threadfence();
        unsigned old = atomicAdd(counter, 1u);
        if (old == 63u) {
            float tot = atomicAdd(g_acc, 0.0f);
            out[0] = tot / (float)BN;
        }
    }
}

extern "C" void kernel_launch(void* const* d_in, const int* in_sizes, int n_in,
                              void* d_out, int out_size, void* d_ws, size_t ws_size,
                              hipStream_t stream) {
    const float* f = (const float*)d_in[0];
    const int* lbl = (const int*)d_in[1];
    char* ws = (char*)d_ws;
    float* sq = (float*)ws;                                    // 32 KB
    short8* fbT = (short8*)(ws + 32768);                       // 2 MB
    float* part = (float*)(ws + 32768 + 2097152);              // 256 KB (8 slices)
    float* pos_d2 = (float*)(ws + 32768 + 2097152 + 262144);   // 32 KB
    float* g_acc = (float*)(ws + 32768 + 2097152 + 262144 + 32768);
    unsigned* counter = (unsigned*)(g_acc + 1);
    float* out = (float*)d_out;

    prep_kernel<<<256, 256, 0, stream>>>(f, fbT, sq, g_acc, counter);
    work_kernel<<<768, 256, 0, stream>>>(fbT, lbl, sq, part, pos_d2);
    merge_kernel<<<64, 128, 0, stream>>>(part, sq, pos_d2, g_acc, counter, out);
}

// Round 14
// 87.738 us; speedup vs baseline: 1.7418x; 1.0168x over previous
//
#include <hip/hip_runtime.h>
#include <math.h>

// TripletHard B=8192 D=128 NC=256. Round-14: mf=4 x nf=2 wave tile (64 rows
// x 32 cols). Halves B-fragment L2 traffic vs mf=2 (268 vs 536 MB: traffic =
// #i-strips x 8192 x 256B) while keeping regs ~155 < lb(256,3)'s 170 cap
// (r7/r8/r9's mf=4 spills all carried nf=4's 64-reg acc; nf=2 halves that).
//   prep : fp32->bf16 (RNE), K-major fbT, sq of rounded values.
//   work : 768 blocks = 256 CU x 3. [0,512): neg-only diff-class min.
//          [512,768): per-class Gram -> 2nd-smallest same-class d2 (pos_d2).
//   merge: combine 16 n1 slices + pos_d2 -> mean hinge (device atomics).
// fbT8[kc*8192 + row] = features[row][kc*8..kc*8+7], kc=0..15.

#define BN 8192
#define MARGIN_F 1.0f
#define EPS_F 1e-5f

typedef __attribute__((ext_vector_type(8))) short short8;
typedef __attribute__((ext_vector_type(4))) float floatx4;

__device__ __forceinline__ unsigned short bf16_rne(float x, float& r) {
    unsigned u = __float_as_uint(x);
    u += 0x7FFF + ((u >> 16) & 1);
    unsigned short h = (unsigned short)(u >> 16);
    r = __uint_as_float(((unsigned)h) << 16);
    return h;
}

// 8 threads/row (256 blocks): bf16 convert, K-major write, sq from ROUNDED
// values. Also zero-inits g_acc/counter.
__global__ __launch_bounds__(256) void prep_kernel(const float* __restrict__ f,
                                                   short8* __restrict__ fbT,
                                                   float* __restrict__ sq,
                                                   float* __restrict__ g_acc,
                                                   unsigned* __restrict__ counter) {
    int gid = blockIdx.x * 256 + threadIdx.x;  // 0..65535
    if (gid == 0) { *g_acc = 0.f; *counter = 0u; }
    int row = gid >> 3, part = gid & 7;
    const float4* f4 = (const float4*)f + (size_t)row * 32 + part * 4;
    float s = 0.f;
#pragma unroll
    for (int cc = 0; cc < 2; ++cc) {  // chunk kc = part*2 + cc
        float4 v0 = f4[cc * 2], v1 = f4[cc * 2 + 1];
        float r0, r1, r2, r3, r4, r5, r6, r7;
        short8 o;
        o[0] = (short)bf16_rne(v0.x, r0);
        o[1] = (short)bf16_rne(v0.y, r1);
        o[2] = (short)bf16_rne(v0.z, r2);
        o[3] = (short)bf16_rne(v0.w, r3);
        o[4] = (short)bf16_rne(v1.x, r4);
        o[5] = (short)bf16_rne(v1.y, r5);
        o[6] = (short)bf16_rne(v1.z, r6);
        o[7] = (short)bf16_rne(v1.w, r7);
        fbT[(size_t)(part * 2 + cc) * BN + row] = o;
        s += r0 * r0 + r1 * r1 + r2 * r2 + r3 * r3 +
             r4 * r4 + r5 * r5 + r6 * r6 + r7 * r7;
    }
    s += __shfl_xor(s, 1, 8);
    s += __shfl_xor(s, 2, 8);
    s += __shfl_xor(s, 4, 8);
    if (part == 0) sq[row] = s;
}

// Fused work kernel. Blocks [0,512): main (gen-1 resident). [512,768): pos.
__global__ __launch_bounds__(256, 3) void work_kernel(const short8* __restrict__ fbT,
                                                      const int* __restrict__ lbl,
                                                      const float* __restrict__ sq,
                                                      float* __restrict__ part,
                                                      float* __restrict__ pos_d2) {
    const int t = threadIdx.x;
    const int lane = t & 63;
    const int wv = t >> 6;
    const int q = lane >> 4, c = lane & 15;
    const int bid = blockIdx.x;

    if (bid >= 512) {
        // ---------------- pos path: per-class 2nd-smallest same-class d2 ---
        __shared__ int midx[256];
        __shared__ int cnt;
        const int cls = bid - 512;
        if (t == 0) cnt = 0;
        __syncthreads();
        for (int r = t; r < BN; r += 256) {
            if (lbl[r] == cls) {
                int p = atomicAdd(&cnt, 1);
                if (p < 256) midx[p] = r;
            }
        }
        __syncthreads();
        int n = cnt < 256 ? cnt : 256;
        if (n == 0) return;
        if (t < 256 && t >= n) midx[t] = midx[0];  // pad
        __syncthreads();

        const int ng = (n + 15) >> 4;  // 16-row groups; wave wv takes ig = wv, wv+4, ...
        for (int ig = wv; ig < ng; ig += 4) {
            short8 a[4];
            int arow = midx[ig * 16 + c];
#pragma unroll
            for (int ks = 0; ks < 4; ++ks)
                a[ks] = fbT[(size_t)(ks * 4 + q) * BN + arow];
            float s1[4], s2[4];
#pragma unroll
            for (int rg = 0; rg < 4; ++rg) { s1[rg] = INFINITY; s2[rg] = INFINITY; }

            for (int s = 0; s < ng; ++s) {  // 16 j-slots per step
                int jslot = s * 16 + c;
                int jrow = midx[jslot];
                short8 b[4];
#pragma unroll
                for (int ks = 0; ks < 4; ++ks)
                    b[ks] = fbT[(size_t)(ks * 4 + q) * BN + jrow];
                float sj = sq[jrow];
                bool valid = (jslot < n);

                floatx4 acc = (floatx4)0.f;
#pragma unroll
                for (int ks = 0; ks < 4; ++ks)
                    acc = __builtin_amdgcn_mfma_f32_16x16x32_bf16(a[ks], b[ks], acc, 0, 0, 0);
#pragma unroll
                for (int rg = 0; rg < 4; ++rg) {
                    float v = fmaf(-2.0f, acc[rg], sj);
                    float vs = valid ? v : INFINITY;
                    s2[rg] = fminf(s2[rg], fmaxf(s1[rg], vs));
                    s1[rg] = fminf(s1[rg], vs);
                }
            }
#pragma unroll
            for (int m = 1; m < 16; m <<= 1) {
#pragma unroll
                for (int rg = 0; rg < 4; ++rg) {
                    float o1 = __shfl_xor(s1[rg], m, 16);
                    float o2 = __shfl_xor(s2[rg], m, 16);
                    float lo = fminf(s1[rg], o1);
                    float hi = fminf(fmaxf(s1[rg], o1), fminf(s2[rg], o2));
                    s1[rg] = lo; s2[rg] = hi;
                }
            }
            if (c == 0) {
#pragma unroll
                for (int rg = 0; rg < 4; ++rg) {
                    int islot = ig * 16 + q * 4 + rg;
                    if (islot < n) {
                        int row = midx[islot];
                        pos_d2[row] = sq[row] + s2[rg];
                    }
                }
            }
        }
        return;
    }

    // --- main path: diff-class min, wave tile 64x32 (mf=4, nf=2), 16 jt ---
    const int i0 = (bid & 31) * 256 + wv * 64;  // 32 i-blocks x 4 waves x 64 rows
    const int g = bid >> 5;  // 0..15
    const int jb = g * 512;

    short8 a[4][4];
#pragma unroll
    for (int mf = 0; mf < 4; ++mf) {
        int row = i0 + mf * 16 + c;
#pragma unroll
        for (int ks = 0; ks < 4; ++ks)
            a[mf][ks] = fbT[(size_t)(ks * 4 + q) * BN + row];
    }
    int li[4][4];
#pragma unroll
    for (int mf = 0; mf < 4; ++mf)
#pragma unroll
        for (int rg = 0; rg < 4; ++rg)
            li[mf][rg] = lbl[i0 + mf * 16 + q * 4 + rg];

    float n1[4][4];
#pragma unroll
    for (int mf = 0; mf < 4; ++mf)
#pragma unroll
        for (int rg = 0; rg < 4; ++rg) n1[mf][rg] = INFINITY;

#pragma unroll 2
    for (int jt = 0; jt < 16; ++jt) {
        const int j0 = jb + jt * 32;

        int ljv[2]; float sjv[2];
#pragma unroll
        for (int nf = 0; nf < 2; ++nf) {
            int jc = j0 + nf * 16 + c;
            ljv[nf] = lbl[jc];
            sjv[nf] = sq[jc];
        }

        floatx4 acc[4][2];
#pragma unroll
        for (int mf = 0; mf < 4; ++mf)
#pragma unroll
            for (int nf = 0; nf < 2; ++nf) acc[mf][nf] = (floatx4)0.f;

#pragma unroll
        for (int ks = 0; ks < 4; ++ks) {
            short8 b[2];
#pragma unroll
            for (int nf = 0; nf < 2; ++nf)
                b[nf] = fbT[(size_t)(ks * 4 + q) * BN + j0 + nf * 16 + c];
#pragma unroll
            for (int mf = 0; mf < 4; ++mf)
#pragma unroll
                for (int nf = 0; nf < 2; ++nf)
                    acc[mf][nf] = __builtin_amdgcn_mfma_f32_16x16x32_bf16(
                        a[mf][ks], b[nf], acc[mf][nf], 0, 0, 0);
        }

        // neg-only epilogue: 4 ops/element
#pragma unroll
        for (int nf = 0; nf < 2; ++nf) {
#pragma unroll
            for (int mf = 0; mf < 4; ++mf)
#pragma unroll
                for (int rg = 0; rg < 4; ++rg) {
                    float v = fmaf(-2.0f, acc[mf][nf][rg], sjv[nf]);
                    float vd = (li[mf][rg] == ljv[nf]) ? INFINITY : v;
                    n1[mf][rg] = fminf(n1[mf][rg], vd);
                }
        }
    }

    // min across the 16 c-lanes sharing each accumulator row
#pragma unroll
    for (int m = 1; m < 16; m <<= 1) {
#pragma unroll
        for (int mf = 0; mf < 4; ++mf)
#pragma unroll
            for (int rg = 0; rg < 4; ++rg)
                n1[mf][rg] = fminf(n1[mf][rg], __shfl_xor(n1[mf][rg], m, 16));
    }
    if (c == 0) {
#pragma unroll
        for (int mf = 0; mf < 4; ++mf)
#pragma unroll
            for (int rg = 0; rg < 4; ++rg)
                part[g * BN + i0 + mf * 16 + q * 4 + rg] = n1[mf][rg];
    }
}

// combine 16 n1 slices + pos_d2 -> hinge; atomic sum; last block writes mean
__global__ __launch_bounds__(128) void merge_kernel(const float* __restrict__ part,
                                                    const float* __restrict__ sq,
                                                    const float* __restrict__ pos_d2,
                                                    float* __restrict__ g_acc,
                                                    unsigned* __restrict__ counter,
                                                    float* __restrict__ out) {
    int r = blockIdx.x * 128 + threadIdx.x;
    float n = INFINITY;
#pragma unroll
    for (int k = 0; k < 16; ++k) n = fminf(n, part[k * BN + r]);
    float si = sq[r];
    float pos = sqrtf(fmaxf(pos_d2[r] + EPS_F, 0.f));
    float neg = sqrtf(fmaxf(si + n + EPS_F, 0.f));
    float h = fmaxf(MARGIN_F + pos - neg, 0.f);
    __shared__ float red[2];
#pragma unroll
    for (int m = 32; m >= 1; m >>= 1) h += __shfl_down(h, m, 64);
    if ((threadIdx.x & 63) == 0) red[threadIdx.x >> 6] = h;
    __syncthreads();
    if (threadIdx.x == 0) {
        atomicAdd(g_acc, red[0] + red[1]);
        __threadfence();
        unsigned old = atomicAdd(counter, 1u);
        if (old == 63u) {
            float tot = atomicAdd(g_acc, 0.0f);
            out[0] = tot / (float)BN;
        }
    }
}

extern "C" void kernel_launch(void* const* d_in, const int* in_sizes, int n_in,
                              void* d_out, int out_size, void* d_ws, size_t ws_size,
                              hipStream_t stream) {
    const float* f = (const float*)d_in[0];
    const int* lbl = (const int*)d_in[1];
    char* ws = (char*)d_ws;
    float* sq = (float*)ws;                                    // 32 KB
    short8* fbT = (short8*)(ws + 32768);                       // 2 MB
    float* part = (float*)(ws + 32768 + 2097152);              // 512 KB (16 slices)
    float* pos_d2 = (float*)(ws + 32768 + 2097152 + 524288);   // 32 KB
    float* g_acc = (float*)(ws + 32768 + 2097152 + 524288 + 32768);
    unsigned* counter = (unsigned*)(g_acc + 1);
    float* out = (float*)d_out;

    prep_kernel<<<256, 256, 0, stream>>>(f, fbT, sq, g_acc, counter);
    work_kernel<<<768, 256, 0, stream>>>(fbT, lbl, sq, part, pos_d2);
    merge_kernel<<<64, 128, 0, stream>>>(part, sq, pos_d2, g_acc, counter, out);
}

// Round 15
// 85.230 us; speedup vs baseline: 1.7931x; 1.0294x over previous
//
#include <hip/hip_runtime.h>
#include <math.h>

// TripletHard B=8192 D=128 NC=256. Round-15: m97-style LDS double-buffered
// B-tile (stage NEXT tile right after barrier; compute CURRENT from LDS;
// __syncthreads at END of body so its vmcnt(0) drain is free — the stage had
// the whole compute to land). Fixes r4's ordering pathology. 4 waves share
// each 32-col tile -> global B-traffic /4 and per-wave L2 latency removed.
//   prep : fp32->bf16 (RNE), K-major fbT, sq of rounded values.
//   work : 768 blocks = 256 CU x 3. [0,512): neg-only diff-class min,
//          wave tile 64x32 (mf=4, nf=2), A-frags resident, B via LDS dbuf.
//          [512,768): per-class Gram -> 2nd-smallest same-class d2 (pos_d2).
//   merge: combine 16 n1 slices + pos_d2 -> mean hinge (device atomics).
// fbT8[kc*8192 + row] = features[row][kc*8..kc*8+7], kc=0..15.

#define BN 8192
#define MARGIN_F 1.0f
#define EPS_F 1e-5f

typedef __attribute__((ext_vector_type(8))) short short8;
typedef __attribute__((ext_vector_type(4))) float floatx4;

__device__ __forceinline__ unsigned short bf16_rne(float x, float& r) {
    unsigned u = __float_as_uint(x);
    u += 0x7FFF + ((u >> 16) & 1);
    unsigned short h = (unsigned short)(u >> 16);
    r = __uint_as_float(((unsigned)h) << 16);
    return h;
}

// 8 threads/row (256 blocks): bf16 convert, K-major write, sq from ROUNDED
// values. Also zero-inits g_acc/counter.
__global__ __launch_bounds__(256) void prep_kernel(const float* __restrict__ f,
                                                   short8* __restrict__ fbT,
                                                   float* __restrict__ sq,
                                                   float* __restrict__ g_acc,
                                                   unsigned* __restrict__ counter) {
    int gid = blockIdx.x * 256 + threadIdx.x;  // 0..65535
    if (gid == 0) { *g_acc = 0.f; *counter = 0u; }
    int row = gid >> 3, part = gid & 7;
    const float4* f4 = (const float4*)f + (size_t)row * 32 + part * 4;
    float s = 0.f;
#pragma unroll
    for (int cc = 0; cc < 2; ++cc) {  // chunk kc = part*2 + cc
        float4 v0 = f4[cc * 2], v1 = f4[cc * 2 + 1];
        float r0, r1, r2, r3, r4, r5, r6, r7;
        short8 o;
        o[0] = (short)bf16_rne(v0.x, r0);
        o[1] = (short)bf16_rne(v0.y, r1);
        o[2] = (short)bf16_rne(v0.z, r2);
        o[3] = (short)bf16_rne(v0.w, r3);
        o[4] = (short)bf16_rne(v1.x, r4);
        o[5] = (short)bf16_rne(v1.y, r5);
        o[6] = (short)bf16_rne(v1.z, r6);
        o[7] = (short)bf16_rne(v1.w, r7);
        fbT[(size_t)(part * 2 + cc) * BN + row] = o;
        s += r0 * r0 + r1 * r1 + r2 * r2 + r3 * r3 +
             r4 * r4 + r5 * r5 + r6 * r6 + r7 * r7;
    }
    s += __shfl_xor(s, 1, 8);
    s += __shfl_xor(s, 2, 8);
    s += __shfl_xor(s, 4, 8);
    if (part == 0) sq[row] = s;
}

// Stage one 32-col B-tile (16 chunks x 32 cols = 8 KB) into LDS: each wave
// issues 2 global_load_lds(16B). LDS dest is wave-uniform; HW adds lane*16.
// Layout: tile[kc*32 + col], kc = lane>>5 within each 64-slot instr.
__device__ __forceinline__ void stage_tile(const short8* __restrict__ fbT,
                                           short8* tile, int j0, int wv, int lane) {
#pragma unroll
    for (int it = 0; it < 2; ++it) {
        int s = wv * 128 + it * 64;  // wave-uniform slot base
        int kc = (s >> 5) + (lane >> 5);
        int col = lane & 31;
        const short8* g = fbT + ((size_t)kc * BN + j0 + col);
        __builtin_amdgcn_global_load_lds(
            (const __attribute__((address_space(1))) void*)g,
            (__attribute__((address_space(3))) void*)(tile + s),
            16, 0, 0);
    }
}

// Fused work kernel. Blocks [0,512): main (gen-1 resident). [512,768): pos.
__global__ __launch_bounds__(256, 3) void work_kernel(const short8* __restrict__ fbT,
                                                      const int* __restrict__ lbl,
                                                      const float* __restrict__ sq,
                                                      float* __restrict__ part,
                                                      float* __restrict__ pos_d2) {
    const int t = threadIdx.x;
    const int lane = t & 63;
    const int wv = t >> 6;
    const int q = lane >> 4, c = lane & 15;
    const int bid = blockIdx.x;

    if (bid >= 512) {
        // ---------------- pos path: per-class 2nd-smallest same-class d2 ---
        __shared__ int midx[256];
        __shared__ int cnt;
        const int cls = bid - 512;
        if (t == 0) cnt = 0;
        __syncthreads();
        for (int r = t; r < BN; r += 256) {
            if (lbl[r] == cls) {
                int p = atomicAdd(&cnt, 1);
                if (p < 256) midx[p] = r;
            }
        }
        __syncthreads();
        int n = cnt < 256 ? cnt : 256;
        if (n == 0) return;
        if (t < 256 && t >= n) midx[t] = midx[0];  // pad
        __syncthreads();

        const int ng = (n + 15) >> 4;  // 16-row groups; wave wv takes ig = wv, wv+4, ...
        for (int ig = wv; ig < ng; ig += 4) {
            short8 a[4];
            int arow = midx[ig * 16 + c];
#pragma unroll
            for (int ks = 0; ks < 4; ++ks)
                a[ks] = fbT[(size_t)(ks * 4 + q) * BN + arow];
            float s1[4], s2[4];
#pragma unroll
            for (int rg = 0; rg < 4; ++rg) { s1[rg] = INFINITY; s2[rg] = INFINITY; }

            for (int s = 0; s < ng; ++s) {  // 16 j-slots per step
                int jslot = s * 16 + c;
                int jrow = midx[jslot];
                short8 b[4];
#pragma unroll
                for (int ks = 0; ks < 4; ++ks)
                    b[ks] = fbT[(size_t)(ks * 4 + q) * BN + jrow];
                float sj = sq[jrow];
                bool valid = (jslot < n);

                floatx4 acc = (floatx4)0.f;
#pragma unroll
                for (int ks = 0; ks < 4; ++ks)
                    acc = __builtin_amdgcn_mfma_f32_16x16x32_bf16(a[ks], b[ks], acc, 0, 0, 0);
#pragma unroll
                for (int rg = 0; rg < 4; ++rg) {
                    float v = fmaf(-2.0f, acc[rg], sj);
                    float vs = valid ? v : INFINITY;
                    s2[rg] = fminf(s2[rg], fmaxf(s1[rg], vs));
                    s1[rg] = fminf(s1[rg], vs);
                }
            }
#pragma unroll
            for (int m = 1; m < 16; m <<= 1) {
#pragma unroll
                for (int rg = 0; rg < 4; ++rg) {
                    float o1 = __shfl_xor(s1[rg], m, 16);
                    float o2 = __shfl_xor(s2[rg], m, 16);
                    float lo = fminf(s1[rg], o1);
                    float hi = fminf(fmaxf(s1[rg], o1), fminf(s2[rg], o2));
                    s1[rg] = lo; s2[rg] = hi;
                }
            }
            if (c == 0) {
#pragma unroll
                for (int rg = 0; rg < 4; ++rg) {
                    int islot = ig * 16 + q * 4 + rg;
                    if (islot < n) {
                        int row = midx[islot];
                        pos_d2[row] = sq[row] + s2[rg];
                    }
                }
            }
        }
        return;
    }

    // --- main path: diff-class min, wave tile 64x32 (mf=4, nf=2), 16 jt ---
    // B-tile shared by the block's 4 waves via double-buffered LDS.
    __shared__ short8 Bt[2][512];  // 2 x 8 KB, [kc*32 + col]

    const int i0 = (bid & 31) * 256 + wv * 64;  // 32 i-blocks x 4 waves x 64 rows
    const int g = bid >> 5;  // 0..15
    const int jb = g * 512;

    stage_tile(fbT, Bt[0], jb, wv, lane);  // tile 0 in flight

    short8 a[4][4];
#pragma unroll
    for (int mf = 0; mf < 4; ++mf) {
        int row = i0 + mf * 16 + c;
#pragma unroll
        for (int ks = 0; ks < 4; ++ks)
            a[mf][ks] = fbT[(size_t)(ks * 4 + q) * BN + row];
    }
    int li[4][4];
#pragma unroll
    for (int mf = 0; mf < 4; ++mf)
#pragma unroll
        for (int rg = 0; rg < 4; ++rg)
            li[mf][rg] = lbl[i0 + mf * 16 + q * 4 + rg];

    float n1[4][4];
#pragma unroll
    for (int mf = 0; mf < 4; ++mf)
#pragma unroll
        for (int rg = 0; rg < 4; ++rg) n1[mf][rg] = INFINITY;

    __syncthreads();  // tile 0 resident (drain also covers a/li loads)

    for (int jt = 0; jt < 16; ++jt) {
        const short8* cur = Bt[jt & 1];
        const int j0 = jb + jt * 32;
        // prefetch next tile NOW; it lands during this tile's compute
        if (jt < 15) stage_tile(fbT, Bt[1 - (jt & 1)], j0 + 32, wv, lane);

        int ljv[2]; float sjv[2];
#pragma unroll
        for (int nf = 0; nf < 2; ++nf) {
            int jc = j0 + nf * 16 + c;
            ljv[nf] = lbl[jc];
            sjv[nf] = sq[jc];
        }

        floatx4 acc[4][2];
#pragma unroll
        for (int mf = 0; mf < 4; ++mf)
#pragma unroll
            for (int nf = 0; nf < 2; ++nf) acc[mf][nf] = (floatx4)0.f;

#pragma unroll
        for (int ks = 0; ks < 4; ++ks) {
            short8 b[2];
#pragma unroll
            for (int nf = 0; nf < 2; ++nf)
                b[nf] = cur[(ks * 4 + q) * 32 + nf * 16 + c];
#pragma unroll
            for (int mf = 0; mf < 4; ++mf)
#pragma unroll
                for (int nf = 0; nf < 2; ++nf)
                    acc[mf][nf] = __builtin_amdgcn_mfma_f32_16x16x32_bf16(
                        a[mf][ks], b[nf], acc[mf][nf], 0, 0, 0);
        }

        // neg-only epilogue: 4 ops/element
#pragma unroll
        for (int nf = 0; nf < 2; ++nf) {
#pragma unroll
            for (int mf = 0; mf < 4; ++mf)
#pragma unroll
                for (int rg = 0; rg < 4; ++rg) {
                    float v = fmaf(-2.0f, acc[mf][nf][rg], sjv[nf]);
                    float vd = (li[mf][rg] == ljv[nf]) ? INFINITY : v;
                    n1[mf][rg] = fminf(n1[mf][rg], vd);
                }
        }
        // barrier at END: stage had the whole compute to land, so the
        // implicit vmcnt(0) drain is (nearly) free; also protects cur reuse.
        __syncthreads();
    }

    // min across the 16 c-lanes sharing each accumulator row
#pragma unroll
    for (int m = 1; m < 16; m <<= 1) {
#pragma unroll
        for (int mf = 0; mf < 4; ++mf)
#pragma unroll
            for (int rg = 0; rg < 4; ++rg)
                n1[mf][rg] = fminf(n1[mf][rg], __shfl_xor(n1[mf][rg], m, 16));
    }
    if (c == 0) {
#pragma unroll
        for (int mf = 0; mf < 4; ++mf)
#pragma unroll
            for (int rg = 0; rg < 4; ++rg)
                part[g * BN + i0 + mf * 16 + q * 4 + rg] = n1[mf][rg];
    }
}

// combine 16 n1 slices + pos_d2 -> hinge; atomic sum; last block writes mean
__global__ __launch_bounds__(128) void merge_kernel(const float* __restrict__ part,
                                                    const float* __restrict__ sq,
                                                    const float* __restrict__ pos_d2,
                                                    float* __restrict__ g_acc,
                                                    unsigned* __restrict__ counter,
                                                    float* __restrict__ out) {
    int r = blockIdx.x * 128 + threadIdx.x;
    float n = INFINITY;
#pragma unroll
    for (int k = 0; k < 16; ++k) n = fminf(n, part[k * BN + r]);
    float si = sq[r];
    float pos = sqrtf(fmaxf(pos_d2[r] + EPS_F, 0.f));
    float neg = sqrtf(fmaxf(si + n + EPS_F, 0.f));
    float h = fmaxf(MARGIN_F + pos - neg, 0.f);
    __shared__ float red[2];
#pragma unroll
    for (int m = 32; m >= 1; m >>= 1) h += __shfl_down(h, m, 64);
    if ((threadIdx.x & 63) == 0) red[threadIdx.x >> 6] = h;
    __syncthreads();
    if (threadIdx.x == 0) {
        atomicAdd(g_acc, red[0] + red[1]);
        __threadfence();
        unsigned old = atomicAdd(counter, 1u);
        if (old == 63u) {
            float tot = atomicAdd(g_acc, 0.0f);
            out[0] = tot / (float)BN;
        }
    }
}

extern "C" void kernel_launch(void* const* d_in, const int* in_sizes, int n_in,
                              void* d_out, int out_size, void* d_ws, size_t ws_size,
                              hipStream_t stream) {
    const float* f = (const float*)d_in[0];
    const int* lbl = (const int*)d_in[1];
    char* ws = (char*)d_ws;
    float* sq = (float*)ws;                                    // 32 KB
    short8* fbT = (short8*)(ws + 32768);                       // 2 MB
    float* part = (float*)(ws + 32768 + 2097152);              // 512 KB (16 slices)
    float* pos_d2 = (float*)(ws + 32768 + 2097152 + 524288);   // 32 KB
    float* g_acc = (float*)(ws + 32768 + 2097152 + 524288 + 32768);
    unsigned* counter = (unsigned*)(g_acc + 1);
    float* out = (float*)d_out;

    prep_kernel<<<256, 256, 0, stream>>>(f, fbT, sq, g_acc, counter);
    work_kernel<<<768, 256, 0, stream>>>(fbT, lbl, sq, part, pos_d2);
    merge_kernel<<<64, 128, 0, stream>>>(part, sq, pos_d2, g_acc, counter, out);
}

// Round 16
// 83.314 us; speedup vs baseline: 1.8343x; 1.0230x over previous
//
#include <hip/hip_runtime.h>
#include <math.h>

// TripletHard B=8192 D=128 NC=256. Round-16 = r15 (LDS dbuf B-tile, proven)
// + lsq float2 (sq,lbl) staged ONCE per block into LDS -> zero global loads
// inside the jt loop except the tile prefetch (keeps the in-order vmcnt queue
// clean so the end-of-body barrier drain stays free).
//   prep : fp32->bf16 (RNE), K-major fbT, lsq=(sq,lblbits) of rounded values.
//   work : 768 blocks = 256 CU x 3. [0,512): neg-only diff-class min,
//          wave tile 64x32 (mf=4, nf=2), A-frags resident, B via LDS dbuf.
//          [512,768): per-class Gram -> 2nd-smallest same-class d2 (pos_d2).
//   merge: combine 16 n1 slices + pos_d2 -> mean hinge (device atomics).
// fbT8[kc*8192 + row] = features[row][kc*8..kc*8+7], kc=0..15.

#define BN 8192
#define MARGIN_F 1.0f
#define EPS_F 1e-5f

typedef __attribute__((ext_vector_type(8))) short short8;
typedef __attribute__((ext_vector_type(4))) float floatx4;

__device__ __forceinline__ unsigned short bf16_rne(float x, float& r) {
    unsigned u = __float_as_uint(x);
    u += 0x7FFF + ((u >> 16) & 1);
    unsigned short h = (unsigned short)(u >> 16);
    r = __uint_as_float(((unsigned)h) << 16);
    return h;
}

// 8 threads/row (256 blocks): bf16 convert, K-major write, lsq=(sq, lblbits)
// from ROUNDED values. Also zero-inits g_acc/counter.
__global__ __launch_bounds__(256) void prep_kernel(const float* __restrict__ f,
                                                   const int* __restrict__ lbl,
                                                   short8* __restrict__ fbT,
                                                   float2* __restrict__ lsq,
                                                   float* __restrict__ g_acc,
                                                   unsigned* __restrict__ counter) {
    int gid = blockIdx.x * 256 + threadIdx.x;  // 0..65535
    if (gid == 0) { *g_acc = 0.f; *counter = 0u; }
    int row = gid >> 3, part = gid & 7;
    const float4* f4 = (const float4*)f + (size_t)row * 32 + part * 4;
    float s = 0.f;
#pragma unroll
    for (int cc = 0; cc < 2; ++cc) {  // chunk kc = part*2 + cc
        float4 v0 = f4[cc * 2], v1 = f4[cc * 2 + 1];
        float r0, r1, r2, r3, r4, r5, r6, r7;
        short8 o;
        o[0] = (short)bf16_rne(v0.x, r0);
        o[1] = (short)bf16_rne(v0.y, r1);
        o[2] = (short)bf16_rne(v0.z, r2);
        o[3] = (short)bf16_rne(v0.w, r3);
        o[4] = (short)bf16_rne(v1.x, r4);
        o[5] = (short)bf16_rne(v1.y, r5);
        o[6] = (short)bf16_rne(v1.z, r6);
        o[7] = (short)bf16_rne(v1.w, r7);
        fbT[(size_t)(part * 2 + cc) * BN + row] = o;
        s += r0 * r0 + r1 * r1 + r2 * r2 + r3 * r3 +
             r4 * r4 + r5 * r5 + r6 * r6 + r7 * r7;
    }
    s += __shfl_xor(s, 1, 8);
    s += __shfl_xor(s, 2, 8);
    s += __shfl_xor(s, 4, 8);
    if (part == 0) {
        float2 p;
        p.x = s;
        p.y = __int_as_float(lbl[row]);
        lsq[row] = p;
    }
}

// Stage one 32-col B-tile (16 chunks x 32 cols = 8 KB) into LDS: each wave
// issues 2 global_load_lds(16B). LDS dest is wave-uniform; HW adds lane*16.
// Layout: tile[kc*32 + col], kc = lane>>5 within each 64-slot instr.
__device__ __forceinline__ void stage_tile(const short8* __restrict__ fbT,
                                           short8* tile, int j0, int wv, int lane) {
#pragma unroll
    for (int it = 0; it < 2; ++it) {
        int s = wv * 128 + it * 64;  // wave-uniform slot base
        int kc = (s >> 5) + (lane >> 5);
        int col = lane & 31;
        const short8* g = fbT + ((size_t)kc * BN + j0 + col);
        __builtin_amdgcn_global_load_lds(
            (const __attribute__((address_space(1))) void*)g,
            (__attribute__((address_space(3))) void*)(tile + s),
            16, 0, 0);
    }
}

// Fused work kernel. Blocks [0,512): main (gen-1 resident). [512,768): pos.
__global__ __launch_bounds__(256, 3) void work_kernel(const short8* __restrict__ fbT,
                                                      const int* __restrict__ lbl,
                                                      const float2* __restrict__ lsq,
                                                      float* __restrict__ part,
                                                      float* __restrict__ pos_d2) {
    const int t = threadIdx.x;
    const int lane = t & 63;
    const int wv = t >> 6;
    const int q = lane >> 4, c = lane & 15;
    const int bid = blockIdx.x;

    if (bid >= 512) {
        // ---------------- pos path: per-class 2nd-smallest same-class d2 ---
        __shared__ int midx[256];
        __shared__ int cnt;
        const int cls = bid - 512;
        if (t == 0) cnt = 0;
        __syncthreads();
        for (int r = t; r < BN; r += 256) {
            if (lbl[r] == cls) {
                int p = atomicAdd(&cnt, 1);
                if (p < 256) midx[p] = r;
            }
        }
        __syncthreads();
        int n = cnt < 256 ? cnt : 256;
        if (n == 0) return;
        if (t < 256 && t >= n) midx[t] = midx[0];  // pad
        __syncthreads();

        const int ng = (n + 15) >> 4;  // 16-row groups; wave wv takes ig = wv, wv+4, ...
        for (int ig = wv; ig < ng; ig += 4) {
            short8 a[4];
            int arow = midx[ig * 16 + c];
#pragma unroll
            for (int ks = 0; ks < 4; ++ks)
                a[ks] = fbT[(size_t)(ks * 4 + q) * BN + arow];
            float s1[4], s2[4];
#pragma unroll
            for (int rg = 0; rg < 4; ++rg) { s1[rg] = INFINITY; s2[rg] = INFINITY; }

            for (int s = 0; s < ng; ++s) {  // 16 j-slots per step
                int jslot = s * 16 + c;
                int jrow = midx[jslot];
                short8 b[4];
#pragma unroll
                for (int ks = 0; ks < 4; ++ks)
                    b[ks] = fbT[(size_t)(ks * 4 + q) * BN + jrow];
                float sj = lsq[jrow].x;
                bool valid = (jslot < n);

                floatx4 acc = (floatx4)0.f;
#pragma unroll
                for (int ks = 0; ks < 4; ++ks)
                    acc = __builtin_amdgcn_mfma_f32_16x16x32_bf16(a[ks], b[ks], acc, 0, 0, 0);
#pragma unroll
                for (int rg = 0; rg < 4; ++rg) {
                    float v = fmaf(-2.0f, acc[rg], sj);
                    float vs = valid ? v : INFINITY;
                    s2[rg] = fminf(s2[rg], fmaxf(s1[rg], vs));
                    s1[rg] = fminf(s1[rg], vs);
                }
            }
#pragma unroll
            for (int m = 1; m < 16; m <<= 1) {
#pragma unroll
                for (int rg = 0; rg < 4; ++rg) {
                    float o1 = __shfl_xor(s1[rg], m, 16);
                    float o2 = __shfl_xor(s2[rg], m, 16);
                    float lo = fminf(s1[rg], o1);
                    float hi = fminf(fmaxf(s1[rg], o1), fminf(s2[rg], o2));
                    s1[rg] = lo; s2[rg] = hi;
                }
            }
            if (c == 0) {
#pragma unroll
                for (int rg = 0; rg < 4; ++rg) {
                    int islot = ig * 16 + q * 4 + rg;
                    if (islot < n) {
                        int row = midx[islot];
                        pos_d2[row] = lsq[row].x + s2[rg];
                    }
                }
            }
        }
        return;
    }

    // --- main path: diff-class min, wave tile 64x32 (mf=4, nf=2), 16 jt ---
    __shared__ short8 Bt[2][512];    // 2 x 8 KB, [kc*32 + col]
    __shared__ float2 lsq_sh[512];   // block's j-stripe (sq, lblbits)

    const int i0 = (bid & 31) * 256 + wv * 64;  // 32 i-blocks x 4 waves x 64 rows
    const int g = bid >> 5;  // 0..15
    const int jb = g * 512;

    stage_tile(fbT, Bt[0], jb, wv, lane);  // tile 0 in flight

    // stage the whole stripe's (sq,label) once: 512 float2, 2 per thread
    lsq_sh[t] = lsq[jb + t];
    lsq_sh[t + 256] = lsq[jb + t + 256];

    short8 a[4][4];
#pragma unroll
    for (int mf = 0; mf < 4; ++mf) {
        int row = i0 + mf * 16 + c;
#pragma unroll
        for (int ks = 0; ks < 4; ++ks)
            a[mf][ks] = fbT[(size_t)(ks * 4 + q) * BN + row];
    }
    int li[4][4];
#pragma unroll
    for (int mf = 0; mf < 4; ++mf)
#pragma unroll
        for (int rg = 0; rg < 4; ++rg)
            li[mf][rg] = __float_as_int(lsq[i0 + mf * 16 + q * 4 + rg].y);

    float n1[4][4];
#pragma unroll
    for (int mf = 0; mf < 4; ++mf)
#pragma unroll
        for (int rg = 0; rg < 4; ++rg) n1[mf][rg] = INFINITY;

    __syncthreads();  // tile 0 + lsq_sh resident

    for (int jt = 0; jt < 16; ++jt) {
        const short8* cur = Bt[jt & 1];
        const int j0 = jb + jt * 32;
        // prefetch next tile NOW; it lands during this tile's compute
        if (jt < 15) stage_tile(fbT, Bt[1 - (jt & 1)], j0 + 32, wv, lane);

        int ljv[2]; float sjv[2];
#pragma unroll
        for (int nf = 0; nf < 2; ++nf) {
            float2 p = lsq_sh[jt * 32 + nf * 16 + c];  // LDS, no global latency
            sjv[nf] = p.x;
            ljv[nf] = __float_as_int(p.y);
        }

        floatx4 acc[4][2];
#pragma unroll
        for (int mf = 0; mf < 4; ++mf)
#pragma unroll
            for (int nf = 0; nf < 2; ++nf) acc[mf][nf] = (floatx4)0.f;

#pragma unroll
        for (int ks = 0; ks < 4; ++ks) {
            short8 b[2];
#pragma unroll
            for (int nf = 0; nf < 2; ++nf)
                b[nf] = cur[(ks * 4 + q) * 32 + nf * 16 + c];
#pragma unroll
            for (int mf = 0; mf < 4; ++mf)
#pragma unroll
                for (int nf = 0; nf < 2; ++nf)
                    acc[mf][nf] = __builtin_amdgcn_mfma_f32_16x16x32_bf16(
                        a[mf][ks], b[nf], acc[mf][nf], 0, 0, 0);
        }

        // neg-only epilogue: 4 ops/element
#pragma unroll
        for (int nf = 0; nf < 2; ++nf) {
#pragma unroll
            for (int mf = 0; mf < 4; ++mf)
#pragma unroll
                for (int rg = 0; rg < 4; ++rg) {
                    float v = fmaf(-2.0f, acc[mf][nf][rg], sjv[nf]);
                    float vd = (li[mf][rg] == ljv[nf]) ? INFINITY : v;
                    n1[mf][rg] = fminf(n1[mf][rg], vd);
                }
        }
        // barrier at END: stage had the whole compute to land -> drain ~free
        __syncthreads();
    }

    // min across the 16 c-lanes sharing each accumulator row
#pragma unroll
    for (int m = 1; m < 16; m <<= 1) {
#pragma unroll
        for (int mf = 0; mf < 4; ++mf)
#pragma unroll
            for (int rg = 0; rg < 4; ++rg)
                n1[mf][rg] = fminf(n1[mf][rg], __shfl_xor(n1[mf][rg], m, 16));
    }
    if (c == 0) {
#pragma unroll
        for (int mf = 0; mf < 4; ++mf)
#pragma unroll
            for (int rg = 0; rg < 4; ++rg)
                part[g * BN + i0 + mf * 16 + q * 4 + rg] = n1[mf][rg];
    }
}

// combine 16 n1 slices + pos_d2 -> hinge; atomic sum; last block writes mean
__global__ __launch_bounds__(128) void merge_kernel(const float* __restrict__ part,
                                                    const float2* __restrict__ lsq,
                                                    const float* __restrict__ pos_d2,
                                                    float* __restrict__ g_acc,
                                                    unsigned* __restrict__ counter,
                                                    float* __restrict__ out) {
    int r = blockIdx.x * 128 + threadIdx.x;
    float n = INFINITY;
#pragma unroll
    for (int k = 0; k < 16; ++k) n = fminf(n, part[k * BN + r]);
    float si = lsq[r].x;
    float pos = sqrtf(fmaxf(pos_d2[r] + EPS_F, 0.f));
    float neg = sqrtf(fmaxf(si + n + EPS_F, 0.f));
    float h = fmaxf(MARGIN_F + pos - neg, 0.f);
    __shared__ float red[2];
#pragma unroll
    for (int m = 32; m >= 1; m >>= 1) h += __shfl_down(h, m, 64);
    if ((threadIdx.x & 63) == 0) red[threadIdx.x >> 6] = h;
    __syncthreads();
    if (threadIdx.x == 0) {
        atomicAdd(g_acc, red[0] + red[1]);
        __threadfence();
        unsigned old = atomicAdd(counter, 1u);
        if (old == 63u) {
            float tot = atomicAdd(g_acc, 0.0f);
            out[0] = tot / (float)BN;
        }
    }
}

extern "C" void kernel_launch(void* const* d_in, const int* in_sizes, int n_in,
                              void* d_out, int out_size, void* d_ws, size_t ws_size,
                              hipStream_t stream) {
    const float* f = (const float*)d_in[0];
    const int* lbl = (const int*)d_in[1];
    char* ws = (char*)d_ws;
    float2* lsq = (float2*)ws;                                 // 64 KB
    short8* fbT = (short8*)(ws + 65536);                       // 2 MB
    float* part = (float*)(ws + 65536 + 2097152);              // 512 KB (16 slices)
    float* pos_d2 = (float*)(ws + 65536 + 2097152 + 524288);   // 32 KB
    float* g_acc = (float*)(ws + 65536 + 2097152 + 524288 + 32768);
    unsigned* counter = (unsigned*)(g_acc + 1);
    float* out = (float*)d_out;

    prep_kernel<<<256, 256, 0, stream>>>(f, lbl, fbT, lsq, g_acc, counter);
    work_kernel<<<768, 256, 0, stream>>>(fbT, lbl, lsq, part, pos_d2);
    merge_kernel<<<64, 128, 0, stream>>>(part, lsq, pos_d2, g_acc, counter, out);
}